// Round 9
// baseline (16.743 us; speedup 1.0000x reference)
//
#include <hip/hip_runtime.h>
#include <math.h>

#define TPB 512   // 8 waves per block; 2 waves per image -> 4 images/block; grid = ceil(B/4)

typedef __fp16 half2v __attribute__((ext_vector_type(2)));
typedef __fp16 half4v __attribute__((ext_vector_type(4)));
typedef __fp16 half8v __attribute__((ext_vector_type(8)));

// DPP-based wave64 sum (pure VALU, no LDS pipe). ctrl/rmask must be literal constants.
template <int CTRL, int RMASK>
__device__ inline float dpp_add(float v) {
    int t = __builtin_amdgcn_update_dpp(0, __float_as_int(v), CTRL, RMASK, 0xf, false);
    return v + __int_as_float(t);
}
__device__ inline float wave_sum_bcast(float v) {
    v = dpp_add<0x111, 0xf>(v);  // row_shr:1
    v = dpp_add<0x112, 0xf>(v);  // row_shr:2
    v = dpp_add<0x114, 0xf>(v);  // row_shr:4
    v = dpp_add<0x118, 0xf>(v);  // row_shr:8  -> lane15 of each row = row sum
    v = dpp_add<0x142, 0xa>(v);  // row_bcast15 into rows 1,3
    v = dpp_add<0x143, 0xc>(v);  // row_bcast31 into rows 2,3 -> lane 63 = total
    return __int_as_float(__builtin_amdgcn_readlane(__float_as_int(v), 63));
}

#if __has_builtin(__builtin_amdgcn_fdot2)
#define HAVE_FDOT2 1
#else
#define HAVE_FDOT2 0
#endif

__global__ __launch_bounds__(TPB, 4) void quanv_one_kernel(
    const float* __restrict__ x,       // (B,784)
    const float* __restrict__ params,  // (L,4)
    const float* __restrict__ W,       // (10,1568)
    const float* __restrict__ bias,    // (10,)
    float* __restrict__ out,           // (B,10)
    int B, int L)
{
    // f16 packed weights: wlds[(c*196+t)*8 + k]; k<4: W[c][4t+k] (quantum),
    // k>=4: W[c][784 + cf(pixel 4t+k-4)] (classical, permuted to pixel order)
    __shared__ __align__(16) __fp16 wlds[15680];
    __shared__ __align__(16) float umat[32];   // folded U_u[16], U_v[16]
    __shared__ float red[8][10];               // per-wave partial logits

    const int tid  = threadIdx.x;
    const int lane = tid & 63;
    const int wv   = tid >> 6;

    // ---- cooperative W pack: 15680 halves = 3920 half4 groups ----
    for (int g = tid; g < 3920; g += TPB) {
        int flat = g * 4;                 // half index
        int c  = flat / 1568;
        int r  = flat - c * 1568;
        int t  = r >> 3;
        int kh = r & 7;                   // 0 (quantum) or 4 (classical)
        half4v o;
        if (kh == 0) {
            float4 q = *(const float4*)(W + c * 1568 + t * 4);
            o[0] = (__fp16)q.x; o[1] = (__fp16)q.y;
            o[2] = (__fp16)q.z; o[3] = (__fp16)q.w;
        } else {
#pragma unroll
            for (int k = 0; k < 4; ++k) {
                int p = t * 4 + k;
                int row = p / 28, col = p - row * 28;
                int gf = (((row & 3) * 4 + (col & 3)) * 7 + (row >> 2)) * 7 + (col >> 2);
                o[k] = (__fp16)W[c * 1568 + 784 + gf];
            }
        }
        *(half4v*)(wlds + flat) = o;
    }

    // ---- fold variational layers into 4x4 U per factor (lanes 0,1 of wave 0) ----
    if (tid < 2) {
        const int f = tid;                // 0: wires{0,1}, 1: wires{2,3}
        float M[16];
#pragma unroll
        for (int i = 0; i < 16; ++i) M[i] = (i % 5 == 0) ? 1.f : 0.f;
        for (int l = 0; l < L; ++l) {
            float A = params[4 * l + 2 * f + 0] * 0.5f;
            float C = __cosf(A), S = __sinf(A);
#pragma unroll
            for (int q = 0; q < 4; ++q) {  // RY hi wire: rows (0,2),(1,3)
                float a0 = M[q],     a2 = M[8 + q];
                M[q]      = C * a0 - S * a2;  M[8 + q]  = S * a0 + C * a2;
                float a1 = M[4 + q], a3 = M[12 + q];
                M[4 + q]  = C * a1 - S * a3;  M[12 + q] = S * a1 + C * a3;
            }
            A = params[4 * l + 2 * f + 1] * 0.5f;
            C = __cosf(A); S = __sinf(A);
#pragma unroll
            for (int q = 0; q < 4; ++q) {  // RY lo wire: rows (0,1),(2,3)
                float a0 = M[q],     a1 = M[4 + q];
                M[q]      = C * a0 - S * a1;  M[4 + q]  = S * a0 + C * a1;
                float a2 = M[8 + q], a3 = M[12 + q];
                M[8 + q]  = C * a2 - S * a3;  M[12 + q] = S * a2 + C * a3;
            }
#pragma unroll
            for (int q = 0; q < 4; ++q) {  // CNOT: swap rows 2,3
                float tm = M[8 + q]; M[8 + q] = M[12 + q]; M[12 + q] = tm;
            }
        }
#pragma unroll
        for (int i = 0; i < 16; ++i) umat[f * 16 + i] = M[i];
    }

    __syncthreads();

    // ---- wave -> (image, half) mapping: 2 waves per image ----
    const int imgIdx = blockIdx.x * 4 + (wv >> 1);
    const int half   = wv & 1;                 // chunk range [98*half, 98*(half+1))
    const int img    = (imgIdx < B) ? imgIdx : (B - 1);   // clamp (keep barriers uniform)

    // U into registers (LDS broadcast reads)
    float Um[32];
#pragma unroll
    for (int j = 0; j < 8; ++j) ((float4*)Um)[j] = ((const float4*)umat)[j];

    const float* xb = x + (size_t)img * 784;

    float acc[10];
#pragma unroll
    for (int c = 0; c < 10; ++c) acc[c] = 0.f;

    const int tlim = 98 * (half + 1);
#pragma unroll
    for (int r = 0; r < 2; ++r) {
        int t = 98 * half + r * 64 + lane;
        if (t < tlim) {
            int pi = t / 14, pj = t - pi * 14;
            float2 top = *(const float2*)(xb + 56 * pi + 2 * pj);
            float2 bot = *(const float2*)(xb + 56 * pi + 2 * pj + 28);
            float4 cim = *(const float4*)(xb + 4 * t);   // classical pixels for chunk t

            float c0 = __cosf(0.5f * top.x), s0 = __sinf(0.5f * top.x);
            float c1 = __cosf(0.5f * top.y), s1 = __sinf(0.5f * top.y);
            float c2 = __cosf(0.5f * bot.x), s2 = __sinf(0.5f * bot.x);
            float c3 = __cosf(0.5f * bot.y), s3 = __sinf(0.5f * bot.y);

            float ui0 = c0 * c1, ui1 = c0 * s1, ui2 = s0 * c1, ui3 = s0 * s1;
            float vi0 = c2 * c3, vi1 = c2 * s3, vi2 = s2 * c3, vi3 = s2 * s3;

            float uf0 = fmaf(Um[0],  ui0, fmaf(Um[1],  ui1, fmaf(Um[2],  ui2, Um[3]  * ui3)));
            float uf1 = fmaf(Um[4],  ui0, fmaf(Um[5],  ui1, fmaf(Um[6],  ui2, Um[7]  * ui3)));
            float uf2 = fmaf(Um[8],  ui0, fmaf(Um[9],  ui1, fmaf(Um[10], ui2, Um[11] * ui3)));
            float uf3 = fmaf(Um[12], ui0, fmaf(Um[13], ui1, fmaf(Um[14], ui2, Um[15] * ui3)));
            float vf0 = fmaf(Um[16], vi0, fmaf(Um[17], vi1, fmaf(Um[18], vi2, Um[19] * vi3)));
            float vf1 = fmaf(Um[20], vi0, fmaf(Um[21], vi1, fmaf(Um[22], vi2, Um[23] * vi3)));
            float vf2 = fmaf(Um[24], vi0, fmaf(Um[25], vi1, fmaf(Um[26], vi2, Um[27] * vi3)));
            float vf3 = fmaf(Um[28], vi0, fmaf(Um[29], vi1, fmaf(Um[30], vi2, Um[31] * vi3)));

            float p0 = uf0 * uf0, p1 = uf1 * uf1, p2 = uf2 * uf2, p3 = uf3 * uf3;
            float q0 = vf0 * vf0, q1 = vf1 * vf1, q2 = vf2 * vf2, q3 = vf3 * vf3;
            float z0 = (p0 + p1) - (p2 + p3);
            float z1 = (p0 + p2) - (p1 + p3);
            float z2 = (q0 + q1) - (q2 + q3);
            float z3 = (q0 + q2) - (q1 + q3);

            half2v f0 = __builtin_amdgcn_cvt_pkrtz(z0, z1);
            half2v f1 = __builtin_amdgcn_cvt_pkrtz(z2, z3);
            half2v f2 = __builtin_amdgcn_cvt_pkrtz(cim.x, cim.y);
            half2v f3 = __builtin_amdgcn_cvt_pkrtz(cim.z, cim.w);

#pragma unroll
            for (int c = 0; c < 10; ++c) {
                half8v w = *(const half8v*)(wlds + (c * 196 + t) * 8);
                half2v w0 = __builtin_shufflevector(w, w, 0, 1);
                half2v w1 = __builtin_shufflevector(w, w, 2, 3);
                half2v w2 = __builtin_shufflevector(w, w, 4, 5);
                half2v w3 = __builtin_shufflevector(w, w, 6, 7);
                float a = acc[c];
#if HAVE_FDOT2
                a = __builtin_amdgcn_fdot2(f0, w0, a, false);
                a = __builtin_amdgcn_fdot2(f1, w1, a, false);
                a = __builtin_amdgcn_fdot2(f2, w2, a, false);
                a = __builtin_amdgcn_fdot2(f3, w3, a, false);
#else
                a = fmaf((float)f0[0], (float)w0[0], a);
                a = fmaf((float)f0[1], (float)w0[1], a);
                a = fmaf((float)f1[0], (float)w1[0], a);
                a = fmaf((float)f1[1], (float)w1[1], a);
                a = fmaf((float)f2[0], (float)w2[0], a);
                a = fmaf((float)f2[1], (float)w2[1], a);
                a = fmaf((float)f3[0], (float)w3[0], a);
                a = fmaf((float)f3[1], (float)w3[1], a);
#endif
                acc[c] = a;
            }
        }
    }

    // ---- per-wave DPP reduction -> LDS ----
    float s0 = wave_sum_bcast(acc[0]);
    float s1 = wave_sum_bcast(acc[1]);
    float s2 = wave_sum_bcast(acc[2]);
    float s3 = wave_sum_bcast(acc[3]);
    float s4 = wave_sum_bcast(acc[4]);
    float s5 = wave_sum_bcast(acc[5]);
    float s6 = wave_sum_bcast(acc[6]);
    float s7 = wave_sum_bcast(acc[7]);
    float s8 = wave_sum_bcast(acc[8]);
    float s9 = wave_sum_bcast(acc[9]);
    if (lane < 10) {
        float o = s0;
        o = (lane == 1) ? s1 : o;
        o = (lane == 2) ? s2 : o;
        o = (lane == 3) ? s3 : o;
        o = (lane == 4) ? s4 : o;
        o = (lane == 5) ? s5 : o;
        o = (lane == 6) ? s6 : o;
        o = (lane == 7) ? s7 : o;
        o = (lane == 8) ? s8 : o;
        o = (lane == 9) ? s9 : o;
        red[wv][lane] = o;
    }
    __syncthreads();

    // ---- even waves: combine both halves, softmax, store ----
    if (half == 0 && imgIdx < B) {
        float lg[10];
#pragma unroll
        for (int c = 0; c < 10; ++c) lg[c] = red[wv][c] + red[wv + 1][c] + bias[c];
        float m = lg[0];
#pragma unroll
        for (int c = 1; c < 10; ++c) m = fmaxf(m, lg[c]);
        float se = 0.f;
#pragma unroll
        for (int c = 0; c < 10; ++c) se += __expf(lg[c] - m);
        float lse = __logf(se) + m;
        if (lane < 10) {
            float o = lg[0];
            o = (lane == 1) ? lg[1] : o;
            o = (lane == 2) ? lg[2] : o;
            o = (lane == 3) ? lg[3] : o;
            o = (lane == 4) ? lg[4] : o;
            o = (lane == 5) ? lg[5] : o;
            o = (lane == 6) ? lg[6] : o;
            o = (lane == 7) ? lg[7] : o;
            o = (lane == 8) ? lg[8] : o;
            o = (lane == 9) ? lg[9] : o;
            out[(size_t)imgIdx * 10 + lane] = o - lse;
        }
    }
}

extern "C" void kernel_launch(void* const* d_in, const int* in_sizes, int n_in,
                              void* d_out, int out_size, void* d_ws, size_t ws_size,
                              hipStream_t stream) {
    const float* x      = (const float*)d_in[0];
    const float* params = (const float*)d_in[1];
    const float* W      = (const float*)d_in[2];
    const float* bias   = (const float*)d_in[3];
    float* out          = (float*)d_out;

    const int B = in_sizes[0] / 784;
    const int L = in_sizes[1] / 4;

    const int nblk = (B + 3) / 4;   // 4 images per block (2 waves/image)
    quanv_one_kernel<<<dim3(nblk), dim3(TPB), 0, stream>>>(x, params, W, bias, out, B, L);
}

// Round 10
// 12.892 us; speedup vs baseline: 1.2987x; 1.2987x over previous
//
#include <hip/hip_runtime.h>
#include <math.h>

#define TPB 512   // 8 waves per block, one image per wave; grid = ceil(B/8) -> 1 block/CU at B=2048

typedef __fp16 half2v __attribute__((ext_vector_type(2)));
typedef __fp16 half4v __attribute__((ext_vector_type(4)));
typedef __fp16 half8v __attribute__((ext_vector_type(8)));

// DPP-based wave64 sum (pure VALU, no LDS pipe). ctrl/rmask must be literal constants.
template <int CTRL, int RMASK>
__device__ inline float dpp_add(float v) {
    int t = __builtin_amdgcn_update_dpp(0, __float_as_int(v), CTRL, RMASK, 0xf, false);
    return v + __int_as_float(t);
}
__device__ inline float wave_sum_bcast(float v) {
    v = dpp_add<0x111, 0xf>(v);  // row_shr:1
    v = dpp_add<0x112, 0xf>(v);  // row_shr:2
    v = dpp_add<0x114, 0xf>(v);  // row_shr:4
    v = dpp_add<0x118, 0xf>(v);  // row_shr:8  -> lane15 of each row = row sum
    v = dpp_add<0x142, 0xa>(v);  // row_bcast15 into rows 1,3
    v = dpp_add<0x143, 0xc>(v);  // row_bcast31 into rows 2,3 -> lane 63 = total
    return __int_as_float(__builtin_amdgcn_readlane(__float_as_int(v), 63));
}

#if __has_builtin(__builtin_amdgcn_fdot2)
#define HAVE_FDOT2 1
#else
#define HAVE_FDOT2 0
#endif

__global__ __launch_bounds__(TPB) void quanv_one_kernel(
    const float* __restrict__ x,       // (B,784)
    const float* __restrict__ params,  // (L,4)
    const float* __restrict__ W,       // (10,1568)
    const float* __restrict__ bias,    // (10,)
    float* __restrict__ out,           // (B,10)
    int B, int L)
{
    // f16 packed weights: wlds[(c*196+t)*8 + k]; k<4: W[c][4t+k] (quantum),
    // k>=4: W[c][784 + cf] where cf's pixel is 4t+(k-4) (classical, pixel order)
    __shared__ __align__(16) __fp16 wlds[15680];
    __shared__ __align__(16) float umat[32];   // folded U_u[16], U_v[16]

    const int tid  = threadIdx.x;
    const int lane = tid & 63;
    const int wv   = tid >> 6;

    // ---- cooperative W pack: ALL global loads coalesced (float4 over source layout),
    //      permutation applied on the LDS-write side (cheap ds scatter) ----
    for (int g = tid; g < 3920; g += TPB) {
        if (g < 1960) {
            // quantum half: source W[c][q0..q0+3], dest contiguous half4
            int e  = g * 4;                // flat over 10*784
            int c  = e / 784;
            int q0 = e - c * 784;
            float4 q = *(const float4*)(W + c * 1568 + q0);
            half4v o;
            o[0] = (__fp16)q.x; o[1] = (__fp16)q.y;
            o[2] = (__fp16)q.z; o[3] = (__fp16)q.w;
            *(half4v*)(wlds + (c * 196 + (q0 >> 2)) * 8) = o;   // ds_write_b64
        } else {
            // classical half: source W[c][784+cf0..cf0+3] (coalesced), scatter to pixel slots
            int e   = (g - 1960) * 4;      // flat over 10*784
            int c   = e / 784;
            int cf0 = e - c * 784;
            float4 q = *(const float4*)(W + c * 1568 + 784 + cf0);
            float qv[4] = {q.x, q.y, q.z, q.w};
#pragma unroll
            for (int d = 0; d < 4; ++d) {
                int cf = cf0 + d;
                int a  = cf / 196;
                int r1 = cf - a * 196;
                int bb = r1 / 49;
                int r2 = r1 - bb * 49;
                int i  = r2 / 7;
                int j  = r2 - i * 7;
                int t  = 28 * i + 7 * a + j;        // pixel>>2
                wlds[(c * 196 + t) * 8 + 4 + bb] = (__fp16)qv[d];  // ds_write_b16
            }
        }
    }

    // ---- fold variational layers into 4x4 U per factor (lanes 0,1 of wave 0) ----
    if (tid < 2) {
        const int f = tid;                // 0: wires{0,1}, 1: wires{2,3}
        float M[16];
#pragma unroll
        for (int i = 0; i < 16; ++i) M[i] = (i % 5 == 0) ? 1.f : 0.f;
        for (int l = 0; l < L; ++l) {
            float A = params[4 * l + 2 * f + 0] * 0.5f;
            float C = __cosf(A), S = __sinf(A);
#pragma unroll
            for (int q = 0; q < 4; ++q) {  // RY hi wire: rows (0,2),(1,3)
                float a0 = M[q],     a2 = M[8 + q];
                M[q]      = C * a0 - S * a2;  M[8 + q]  = S * a0 + C * a2;
                float a1 = M[4 + q], a3 = M[12 + q];
                M[4 + q]  = C * a1 - S * a3;  M[12 + q] = S * a1 + C * a3;
            }
            A = params[4 * l + 2 * f + 1] * 0.5f;
            C = __cosf(A); S = __sinf(A);
#pragma unroll
            for (int q = 0; q < 4; ++q) {  // RY lo wire: rows (0,1),(2,3)
                float a0 = M[q],     a1 = M[4 + q];
                M[q]      = C * a0 - S * a1;  M[4 + q]  = S * a0 + C * a1;
                float a2 = M[8 + q], a3 = M[12 + q];
                M[8 + q]  = C * a2 - S * a3;  M[12 + q] = S * a2 + C * a3;
            }
#pragma unroll
            for (int q = 0; q < 4; ++q) {  // CNOT: swap rows 2,3
                float tm = M[8 + q]; M[8 + q] = M[12 + q]; M[12 + q] = tm;
            }
        }
#pragma unroll
        for (int i = 0; i < 16; ++i) umat[f * 16 + i] = M[i];
    }

    __syncthreads();   // the only block barrier

    const int img = blockIdx.x * 8 + wv;
    if (img >= B) return;

    // U into registers (LDS broadcast reads)
    float Um[32];
#pragma unroll
    for (int j = 0; j < 8; ++j) ((float4*)Um)[j] = ((const float4*)umat)[j];

    const float* xb = x + (size_t)img * 784;

    float acc[10];
#pragma unroll
    for (int c = 0; c < 10; ++c) acc[c] = 0.f;

#pragma unroll
    for (int r = 0; r < 4; ++r) {
        int t = r * 64 + lane;
        if (t < 196) {
            int pi = t / 14, pj = t - pi * 14;
            float2 top = *(const float2*)(xb + 56 * pi + 2 * pj);
            float2 bot = *(const float2*)(xb + 56 * pi + 2 * pj + 28);
            float4 cim = *(const float4*)(xb + 4 * t);   // classical pixels for chunk t

            float c0 = __cosf(0.5f * top.x), s0 = __sinf(0.5f * top.x);
            float c1 = __cosf(0.5f * top.y), s1 = __sinf(0.5f * top.y);
            float c2 = __cosf(0.5f * bot.x), s2 = __sinf(0.5f * bot.x);
            float c3 = __cosf(0.5f * bot.y), s3 = __sinf(0.5f * bot.y);

            float ui0 = c0 * c1, ui1 = c0 * s1, ui2 = s0 * c1, ui3 = s0 * s1;
            float vi0 = c2 * c3, vi1 = c2 * s3, vi2 = s2 * c3, vi3 = s2 * s3;

            float uf0 = fmaf(Um[0],  ui0, fmaf(Um[1],  ui1, fmaf(Um[2],  ui2, Um[3]  * ui3)));
            float uf1 = fmaf(Um[4],  ui0, fmaf(Um[5],  ui1, fmaf(Um[6],  ui2, Um[7]  * ui3)));
            float uf2 = fmaf(Um[8],  ui0, fmaf(Um[9],  ui1, fmaf(Um[10], ui2, Um[11] * ui3)));
            float uf3 = fmaf(Um[12], ui0, fmaf(Um[13], ui1, fmaf(Um[14], ui2, Um[15] * ui3)));
            float vf0 = fmaf(Um[16], vi0, fmaf(Um[17], vi1, fmaf(Um[18], vi2, Um[19] * vi3)));
            float vf1 = fmaf(Um[20], vi0, fmaf(Um[21], vi1, fmaf(Um[22], vi2, Um[23] * vi3)));
            float vf2 = fmaf(Um[24], vi0, fmaf(Um[25], vi1, fmaf(Um[26], vi2, Um[27] * vi3)));
            float vf3 = fmaf(Um[28], vi0, fmaf(Um[29], vi1, fmaf(Um[30], vi2, Um[31] * vi3)));

            float p0 = uf0 * uf0, p1 = uf1 * uf1, p2 = uf2 * uf2, p3 = uf3 * uf3;
            float q0 = vf0 * vf0, q1 = vf1 * vf1, q2 = vf2 * vf2, q3 = vf3 * vf3;
            float z0 = (p0 + p1) - (p2 + p3);
            float z1 = (p0 + p2) - (p1 + p3);
            float z2 = (q0 + q1) - (q2 + q3);
            float z3 = (q0 + q2) - (q1 + q3);

            half2v f0 = __builtin_amdgcn_cvt_pkrtz(z0, z1);
            half2v f1 = __builtin_amdgcn_cvt_pkrtz(z2, z3);
            half2v f2 = __builtin_amdgcn_cvt_pkrtz(cim.x, cim.y);
            half2v f3 = __builtin_amdgcn_cvt_pkrtz(cim.z, cim.w);

#pragma unroll
            for (int c = 0; c < 10; ++c) {
                half8v w = *(const half8v*)(wlds + (c * 196 + t) * 8);
                half2v w0 = __builtin_shufflevector(w, w, 0, 1);
                half2v w1 = __builtin_shufflevector(w, w, 2, 3);
                half2v w2 = __builtin_shufflevector(w, w, 4, 5);
                half2v w3 = __builtin_shufflevector(w, w, 6, 7);
                float a = acc[c];
#if HAVE_FDOT2
                a = __builtin_amdgcn_fdot2(f0, w0, a, false);
                a = __builtin_amdgcn_fdot2(f1, w1, a, false);
                a = __builtin_amdgcn_fdot2(f2, w2, a, false);
                a = __builtin_amdgcn_fdot2(f3, w3, a, false);
#else
                a = fmaf((float)f0[0], (float)w0[0], a);
                a = fmaf((float)f0[1], (float)w0[1], a);
                a = fmaf((float)f1[0], (float)w1[0], a);
                a = fmaf((float)f1[1], (float)w1[1], a);
                a = fmaf((float)f2[0], (float)w2[0], a);
                a = fmaf((float)f2[1], (float)w2[1], a);
                a = fmaf((float)f3[0], (float)w3[0], a);
                a = fmaf((float)f3[1], (float)w3[1], a);
#endif
                acc[c] = a;
            }
        }
    }

    // ---- DPP wave reduction (all-lane uniform results) ----
    float l0 = wave_sum_bcast(acc[0]) + bias[0];
    float l1 = wave_sum_bcast(acc[1]) + bias[1];
    float l2 = wave_sum_bcast(acc[2]) + bias[2];
    float l3 = wave_sum_bcast(acc[3]) + bias[3];
    float l4 = wave_sum_bcast(acc[4]) + bias[4];
    float l5 = wave_sum_bcast(acc[5]) + bias[5];
    float l6 = wave_sum_bcast(acc[6]) + bias[6];
    float l7 = wave_sum_bcast(acc[7]) + bias[7];
    float l8 = wave_sum_bcast(acc[8]) + bias[8];
    float l9 = wave_sum_bcast(acc[9]) + bias[9];

    float m = fmaxf(fmaxf(fmaxf(fmaxf(l0, l1), fmaxf(l2, l3)),
                          fmaxf(fmaxf(l4, l5), fmaxf(l6, l7))),
                    fmaxf(l8, l9));
    float se = __expf(l0 - m) + __expf(l1 - m) + __expf(l2 - m) + __expf(l3 - m) +
               __expf(l4 - m) + __expf(l5 - m) + __expf(l6 - m) + __expf(l7 - m) +
               __expf(l8 - m) + __expf(l9 - m);
    float lse = __logf(se) + m;

    if (lane < 10) {
        float o = l0 - lse;
        o = (lane == 1) ? l1 - lse : o;
        o = (lane == 2) ? l2 - lse : o;
        o = (lane == 3) ? l3 - lse : o;
        o = (lane == 4) ? l4 - lse : o;
        o = (lane == 5) ? l5 - lse : o;
        o = (lane == 6) ? l6 - lse : o;
        o = (lane == 7) ? l7 - lse : o;
        o = (lane == 8) ? l8 - lse : o;
        o = (lane == 9) ? l9 - lse : o;
        out[(size_t)img * 10 + lane] = o;
    }
}

extern "C" void kernel_launch(void* const* d_in, const int* in_sizes, int n_in,
                              void* d_out, int out_size, void* d_ws, size_t ws_size,
                              hipStream_t stream) {
    const float* x      = (const float*)d_in[0];
    const float* params = (const float*)d_in[1];
    const float* W      = (const float*)d_in[2];
    const float* bias   = (const float*)d_in[3];
    float* out          = (float*)d_out;

    const int B = in_sizes[0] / 784;
    const int L = in_sizes[1] / 4;

    const int nblk = (B + 7) / 8;
    quanv_one_kernel<<<dim3(nblk), dim3(TPB), 0, stream>>>(x, params, W, bias, out, B, L);
}